// Round 1
// baseline (692.972 us; speedup 1.0000x reference)
//
#include <hip/hip_runtime.h>
#include <hip/hip_bf16.h>

#define T_TOK 1024
#define HDIM  1024
#define NEXP  64
#define IDIM  512
#define SIDIM 1024
#define NGRP  8
#define GSZ   8
#define TKGN  3
#define TOPKN 6
#define CAPS  14336

typedef __attribute__((ext_vector_type(8))) short bf16x8;
typedef __attribute__((ext_vector_type(4))) float f32x4;

__device__ __forceinline__ short f2bf(float f) {
  union { __hip_bfloat16 h; short s; } u;
  u.h = __float2bfloat16(f);
  return u.s;
}

// ---------------- K0: zero counters ----------------
__global__ void k0_init(int* counts, int* cursor) {
  int i = threadIdx.x;
  if (i < NEXP) { counts[i] = 0; cursor[i] = 0; }
}

// ---------------- K1: gating + grouped top-k ----------------
__global__ __launch_bounds__(64) void k1_gate(
    const float* __restrict__ x, const float* __restrict__ gw,
    const float* __restrict__ ebias,
    int* __restrict__ ids, float* __restrict__ wts, int* __restrict__ counts) {
  int t = blockIdx.x;
  int lane = threadIdx.x;
  const float* xr = x + (size_t)t * HDIM;
  double acc = 0.0;
  for (int h = 0; h < HDIM; ++h)
    acc += (double)xr[h] * (double)gw[h * NEXP + lane];
  float logit = (float)acc;
  float sig = 1.f / (1.f + expf(-logit));
  float sc = sig + ebias[lane];
  __shared__ float s_sc[NEXP], s_sig[NEXP];
  s_sc[lane] = sc; s_sig[lane] = sig;
  __syncthreads();
  if (lane == 0) {
    // group scores = sum of top-2 biased scores per group of 8
    float gsum[NGRP];
    for (int g = 0; g < NGRP; ++g) {
      float m1 = -1e30f; int i1 = -1;
      for (int i = 0; i < GSZ; ++i) {
        float v = s_sc[g * GSZ + i];
        if (v > m1) { m1 = v; i1 = i; }
      }
      float m2 = -1e30f;
      for (int i = 0; i < GSZ; ++i) {
        if (i == i1) continue;
        float v = s_sc[g * GSZ + i];
        if (v > m2) m2 = v;
      }
      gsum[g] = m1 + m2;
    }
    // top-3 groups (ties -> lower index, via strict >)
    unsigned gselmask = 0;
    for (int r = 0; r < TKGN; ++r) {
      float best = -1e30f; int bi = 0;
      for (int g = 0; g < NGRP; ++g) {
        if ((gselmask >> g) & 1) continue;
        if (gsum[g] > best) { best = gsum[g]; bi = g; }
      }
      gselmask |= 1u << bi;
    }
    // top-6 experts among selected groups by biased score
    unsigned long long taken = 0;
    int chosen[TOPKN]; float wsum = 0.f;
    for (int r = 0; r < TOPKN; ++r) {
      float best = -1e30f; int bi = 0;
      for (int e = 0; e < NEXP; ++e) {
        if (!((gselmask >> (e >> 3)) & 1)) continue;
        if ((taken >> e) & 1) continue;
        float v = s_sc[e];
        if (v > best) { best = v; bi = e; }
      }
      taken |= 1ull << bi;
      chosen[r] = bi;
      wsum += s_sig[bi];
    }
    for (int r = 0; r < TOPKN; ++r) {
      ids[t * TOPKN + r] = chosen[r];
      wts[t * TOPKN + r] = s_sig[chosen[r]] / wsum;
      atomicAdd(&counts[chosen[r]], 1);
    }
  }
}

// ---------------- K1b: padded prefix offsets + slot init ----------------
__global__ void k1b_scan(const int* __restrict__ counts, int* __restrict__ eoff,
                         int* __restrict__ slot_tok, float* __restrict__ slot_wt) {
  __shared__ int soff[NEXP + 1];
  int tid = threadIdx.x;
  if (tid == 0) {
    int o = 0;
    for (int e = 0; e < NEXP; ++e) { soff[e] = o; o += ((counts[e] + 127) >> 7) << 7; }
    soff[NEXP] = o;
  }
  __syncthreads();
  if (tid <= NEXP) eoff[tid] = soff[tid];
  int total = soff[NEXP];
  for (int i = tid; i < total; i += blockDim.x) { slot_tok[i] = 0; slot_wt[i] = 0.f; }
}

// ---------------- K1c: fill compact slots ----------------
__global__ void k1c_fill(const int* __restrict__ ids, const float* __restrict__ wts,
                         const int* __restrict__ eoff, int* __restrict__ cursor,
                         int* __restrict__ slot_tok, float* __restrict__ slot_wt) {
  int i = blockIdx.x * blockDim.x + threadIdx.x;
  if (i >= T_TOK * TOPKN) return;
  int e = ids[i];
  int s = eoff[e] + atomicAdd(&cursor[e], 1);
  slot_tok[s] = i / TOPKN;
  slot_wt[s] = wts[i] * 2.5f;  // routed_scaling_factor folded in
}

// ---------------- K2: mid = silu(x@Wg) * (x@Wu)  (per expert, bf16 MFMA) ----
// grid: x = i-chunk (IC/128), y = m-tile (8), z = expert
__global__ __launch_bounds__(512) void k2_mid(
    const float* __restrict__ x, const float* __restrict__ Wg, const float* __restrict__ Wu,
    const int* __restrict__ slot_tok, const int* __restrict__ eoff,
    __hip_bfloat16* __restrict__ mid, int IC) {
  int e = blockIdx.z;
  int base, mcount;
  if (eoff) { base = eoff[e]; mcount = eoff[e + 1] - base; }
  else      { base = 0;       mcount = T_TOK; }
  int mt = blockIdx.y;
  if (mt * 128 >= mcount) return;
  int slotbase = base + mt * 128;
  int ic0 = blockIdx.x * 128;
  const float* wg = Wg + (size_t)e * HDIM * IC;
  const float* wu = Wu + (size_t)e * HDIM * IC;

  __shared__ __align__(16) short As[128 * 72];   // x tile, padded stride 72
  __shared__ __align__(16) short Bg[128 * 64];   // transposed+swizzled [n][k]
  __shared__ __align__(16) short Bu[128 * 64];

  int tid = threadIdx.x;
  int wave = tid >> 6, lane = tid & 63;
  int wm = wave >> 2, wn = wave & 3;
  int lr = lane & 15, lk = lane >> 4;

  f32x4 accg[4][2], accu[4][2];
  for (int a = 0; a < 4; ++a)
    for (int b = 0; b < 2; ++b) { accg[a][b] = (f32x4)0.f; accu[a][b] = (f32x4)0.f; }

  for (int k0 = 0; k0 < HDIM; k0 += 64) {
    __syncthreads();
    // stage A: 128 rows x 64 k, fp32 -> bf16
    for (int g = tid; g < 1024; g += 512) {
      int r = g >> 3, c8 = (g & 7) << 3;
      int tok = slot_tok ? slot_tok[slotbase + r] : (slotbase + r);
      const float* src = x + (size_t)tok * HDIM + k0 + c8;
      float4 v0 = *(const float4*)src;
      float4 v1 = *(const float4*)(src + 4);
      bf16x8 tv;
      tv[0] = f2bf(v0.x); tv[1] = f2bf(v0.y); tv[2] = f2bf(v0.z); tv[3] = f2bf(v0.w);
      tv[4] = f2bf(v1.x); tv[5] = f2bf(v1.y); tv[6] = f2bf(v1.z); tv[7] = f2bf(v1.w);
      *(bf16x8*)&As[r * 72 + c8] = tv;
    }
    // stage Bg/Bu: [64 k][128 n] fp32 -> transposed bf16 LDS [n][k], XOR-swizzled granules
    for (int g = tid; g < 1024; g += 512) {
      int n = g & 127, kg = g >> 7;
      {
        const float* src = wg + (size_t)(k0 + kg * 8) * IC + ic0 + n;
        bf16x8 tv;
        #pragma unroll
        for (int i = 0; i < 8; ++i) tv[i] = f2bf(src[(size_t)i * IC]);
        *(bf16x8*)&Bg[(n * 8 + (kg ^ (n & 7))) * 8] = tv;
      }
      {
        const float* src = wu + (size_t)(k0 + kg * 8) * IC + ic0 + n;
        bf16x8 tv;
        #pragma unroll
        for (int i = 0; i < 8; ++i) tv[i] = f2bf(src[(size_t)i * IC]);
        *(bf16x8*)&Bu[(n * 8 + (kg ^ (n & 7))) * 8] = tv;
      }
    }
    __syncthreads();
    // compute: per wave 64m x 32n tile
    #pragma unroll
    for (int kk = 0; kk < 2; ++kk) {
      bf16x8 af[4];
      #pragma unroll
      for (int mf = 0; mf < 4; ++mf) {
        int row = wm * 64 + mf * 16 + lr;
        af[mf] = *(bf16x8*)&As[row * 72 + kk * 32 + lk * 8];
      }
      #pragma unroll
      for (int nf = 0; nf < 2; ++nf) {
        int col = wn * 32 + nf * 16 + lr;
        int gidx = (col * 8 + ((kk * 4 + lk) ^ (col & 7))) * 8;
        bf16x8 bgf = *(bf16x8*)&Bg[gidx];
        bf16x8 buf_ = *(bf16x8*)&Bu[gidx];
        #pragma unroll
        for (int mf = 0; mf < 4; ++mf) {
          accg[mf][nf] = __builtin_amdgcn_mfma_f32_16x16x32_bf16(af[mf], bgf, accg[mf][nf], 0, 0, 0);
          accu[mf][nf] = __builtin_amdgcn_mfma_f32_16x16x32_bf16(af[mf], buf_, accu[mf][nf], 0, 0, 0);
        }
      }
    }
  }
  // epilogue: silu(g)*u -> bf16 mid
  #pragma unroll
  for (int mf = 0; mf < 4; ++mf)
    #pragma unroll
    for (int nf = 0; nf < 2; ++nf)
      #pragma unroll
      for (int r = 0; r < 4; ++r) {
        int row = wm * 64 + mf * 16 + lk * 4 + r;
        int col = wn * 32 + nf * 16 + lr;
        float gv = accg[mf][nf][r], uv = accu[mf][nf][r];
        float h = gv / (1.f + expf(-gv)) * uv;
        mid[(size_t)(slotbase + row) * IC + ic0 + col] = __float2bfloat16(h);
      }
}

// ---------------- K3: out (+)= (mid @ Wd) * weight ----------------
// grid: x = n-chunk (8), y = m-tile (8), z = expert
template <bool ATOMIC>
__global__ __launch_bounds__(512) void k3_down(
    const __hip_bfloat16* __restrict__ mid, const float* __restrict__ Wd,
    const int* __restrict__ slot_tok, const float* __restrict__ slot_wt,
    const int* __restrict__ eoff, float* __restrict__ out, int KD) {
  int e = blockIdx.z;
  int base, mcount;
  if (eoff) { base = eoff[e]; mcount = eoff[e + 1] - base; }
  else      { base = 0;       mcount = T_TOK; }
  int mt = blockIdx.y;
  if (mt * 128 >= mcount) return;
  int slotbase = base + mt * 128;
  int n0 = blockIdx.x * 128;
  const float* wd = Wd + (size_t)e * KD * HDIM;

  __shared__ __align__(16) short As[128 * 72];
  __shared__ __align__(16) short Bs[128 * 64];

  int tid = threadIdx.x;
  int wave = tid >> 6, lane = tid & 63;
  int wm = wave >> 2, wn = wave & 3;
  int lr = lane & 15, lk = lane >> 4;

  f32x4 acc[4][2];
  for (int a = 0; a < 4; ++a)
    for (int b = 0; b < 2; ++b) acc[a][b] = (f32x4)0.f;

  for (int k0 = 0; k0 < KD; k0 += 64) {
    __syncthreads();
    // stage A from mid (already bf16)
    for (int g = tid; g < 1024; g += 512) {
      int r = g >> 3, c8 = (g & 7) << 3;
      const __hip_bfloat16* src = mid + (size_t)(slotbase + r) * KD + k0 + c8;
      *(bf16x8*)&As[r * 72 + c8] = *(const bf16x8*)src;
    }
    // stage Wd transposed + swizzled
    for (int g = tid; g < 1024; g += 512) {
      int n = g & 127, kg = g >> 7;
      const float* src = wd + (size_t)(k0 + kg * 8) * HDIM + n0 + n;
      bf16x8 tv;
      #pragma unroll
      for (int i = 0; i < 8; ++i) tv[i] = f2bf(src[(size_t)i * HDIM]);
      *(bf16x8*)&Bs[(n * 8 + (kg ^ (n & 7))) * 8] = tv;
    }
    __syncthreads();
    #pragma unroll
    for (int kk = 0; kk < 2; ++kk) {
      bf16x8 af[4];
      #pragma unroll
      for (int mf = 0; mf < 4; ++mf) {
        int row = wm * 64 + mf * 16 + lr;
        af[mf] = *(bf16x8*)&As[row * 72 + kk * 32 + lk * 8];
      }
      #pragma unroll
      for (int nf = 0; nf < 2; ++nf) {
        int col = wn * 32 + nf * 16 + lr;
        bf16x8 bf_ = *(bf16x8*)&Bs[(col * 8 + ((kk * 4 + lk) ^ (col & 7))) * 8];
        #pragma unroll
        for (int mf = 0; mf < 4; ++mf)
          acc[mf][nf] = __builtin_amdgcn_mfma_f32_16x16x32_bf16(af[mf], bf_, acc[mf][nf], 0, 0, 0);
      }
    }
  }
  #pragma unroll
  for (int mf = 0; mf < 4; ++mf)
    #pragma unroll
    for (int nf = 0; nf < 2; ++nf)
      #pragma unroll
      for (int r = 0; r < 4; ++r) {
        int row = wm * 64 + mf * 16 + lk * 4 + r;
        int col = wn * 32 + nf * 16 + lr;
        float v = acc[mf][nf][r];
        if (ATOMIC) {
          int s = slotbase + row;
          float w = slot_wt[s];
          if (w != 0.f) {
            int tok = slot_tok[s];
            atomicAdd(&out[(size_t)tok * HDIM + n0 + col], v * w);
          }
        } else {
          out[(size_t)(slotbase + row) * HDIM + n0 + col] = v;
        }
      }
}

// ---------------- launch ----------------
extern "C" void kernel_launch(void* const* d_in, const int* in_sizes, int n_in,
                              void* d_out, int out_size, void* d_ws, size_t ws_size,
                              hipStream_t stream) {
  (void)in_sizes; (void)n_in; (void)out_size; (void)ws_size;
  const float* x      = (const float*)d_in[0];
  const float* gate_w = (const float*)d_in[1];
  const float* ebias  = (const float*)d_in[2];
  const float* wgate  = (const float*)d_in[3];
  const float* wup    = (const float*)d_in[4];
  const float* wdown  = (const float*)d_in[5];
  const float* swg    = (const float*)d_in[6];
  const float* swu    = (const float*)d_in[7];
  const float* swd    = (const float*)d_in[8];
  float* out = (float*)d_out;

  char* ws = (char*)d_ws;
  int*   counts   = (int*)(ws + 0);
  int*   cursor   = (int*)(ws + 256);
  int*   eoff     = (int*)(ws + 512);
  int*   ids      = (int*)(ws + 1024);
  float* wts      = (float*)(ws + 1024 + 24576);
  int*   slot_tok = (int*)(ws + 50176);
  float* slot_wt  = (float*)(ws + 107520);
  __hip_bfloat16* mid_r = (__hip_bfloat16*)(ws + 164864);
  __hip_bfloat16* mid_s = mid_r + (size_t)CAPS * IDIM;

  k0_init<<<1, 128, 0, stream>>>(counts, cursor);
  k1_gate<<<T_TOK, 64, 0, stream>>>(x, gate_w, ebias, ids, wts, counts);
  k1b_scan<<<1, 256, 0, stream>>>(counts, eoff, slot_tok, slot_wt);
  k1c_fill<<<(T_TOK * TOPKN + 255) / 256, 256, 0, stream>>>(ids, wts, eoff, cursor, slot_tok, slot_wt);
  // routed mid: IC=512 -> 4 chunks
  k2_mid<<<dim3(4, 8, 64), 512, 0, stream>>>(x, wgate, wup, slot_tok, eoff, mid_r, IDIM);
  // shared mid: IC=1024 -> 8 chunks
  k2_mid<<<dim3(8, 8, 1), 512, 0, stream>>>(x, swg, swu, nullptr, nullptr, mid_s, SIDIM);
  // shared down writes out (covers every element)
  k3_down<false><<<dim3(8, 8, 1), 512, 0, stream>>>(mid_s, swd, nullptr, nullptr, nullptr, out, SIDIM);
  // routed down accumulates
  k3_down<true><<<dim3(8, 8, 64), 512, 0, stream>>>(mid_r, wdown, slot_tok, slot_wt, eoff, out, IDIM);
}

// Round 2
// 352.699 us; speedup vs baseline: 1.9648x; 1.9648x over previous
//
#include <hip/hip_runtime.h>
#include <hip/hip_bf16.h>

#define T_TOK 1024
#define HDIM  1024
#define NEXP  64
#define IDIM  512
#define SIDIM 1024
#define NGRP  8
#define GSZ   8
#define TKGN  3
#define TOPKN 6
#define CAPS  14336

typedef __attribute__((ext_vector_type(8))) short bf16x8;
typedef __attribute__((ext_vector_type(4))) float f32x4;

__device__ __forceinline__ short f2bf(float f) {
  union { __hip_bfloat16 h; short s; } u;
  u.h = __float2bfloat16(f);
  return u.s;
}

// ---------------- K0: zero counters + zero out ----------------
__global__ void k0_init(int* counts, int* cursor, float4* out4) {
  int gid = blockIdx.x * blockDim.x + threadIdx.x;
  if (gid < NEXP) { counts[gid] = 0; cursor[gid] = 0; }
  int total4 = T_TOK * HDIM / 4;
  int stride = gridDim.x * blockDim.x;
  for (int i = gid; i < total4; i += stride)
    out4[i] = make_float4(0.f, 0.f, 0.f, 0.f);
}

// ---------------- K1: gating + grouped top-k (4 tokens / block) -------------
__global__ __launch_bounds__(256) void k1_gate(
    const float* __restrict__ x, const float* __restrict__ gw,
    const float* __restrict__ ebias,
    int* __restrict__ ids, float* __restrict__ wts, int* __restrict__ counts) {
  int sub = threadIdx.x >> 6;
  int lane = threadIdx.x & 63;
  int t = blockIdx.x * 4 + sub;
  const float* xr = x + (size_t)t * HDIM;
  double acc = 0.0;
  for (int h = 0; h < HDIM; ++h)
    acc += (double)xr[h] * (double)gw[h * NEXP + lane];
  float logit = (float)acc;
  float sig = 1.f / (1.f + expf(-logit));
  float sc = sig + ebias[lane];
  __shared__ float s_sc[4][NEXP], s_sig[4][NEXP];
  s_sc[sub][lane] = sc; s_sig[sub][lane] = sig;
  __syncthreads();
  if (lane == 0) {
    const float* ssc = s_sc[sub];
    const float* ssig = s_sig[sub];
    float gsum[NGRP];
    for (int g = 0; g < NGRP; ++g) {
      float m1 = -1e30f; int i1 = -1;
      for (int i = 0; i < GSZ; ++i) {
        float v = ssc[g * GSZ + i];
        if (v > m1) { m1 = v; i1 = i; }
      }
      float m2 = -1e30f;
      for (int i = 0; i < GSZ; ++i) {
        if (i == i1) continue;
        float v = ssc[g * GSZ + i];
        if (v > m2) m2 = v;
      }
      gsum[g] = m1 + m2;
    }
    unsigned gselmask = 0;
    for (int r = 0; r < TKGN; ++r) {
      float best = -1e30f; int bi = 0;
      for (int g = 0; g < NGRP; ++g) {
        if ((gselmask >> g) & 1) continue;
        if (gsum[g] > best) { best = gsum[g]; bi = g; }
      }
      gselmask |= 1u << bi;
    }
    unsigned long long taken = 0;
    int chosen[TOPKN]; float wsum = 0.f;
    for (int r = 0; r < TOPKN; ++r) {
      float best = -1e30f; int bi = 0;
      for (int e = 0; e < NEXP; ++e) {
        if (!((gselmask >> (e >> 3)) & 1)) continue;
        if ((taken >> e) & 1) continue;
        float v = ssc[e];
        if (v > best) { best = v; bi = e; }
      }
      taken |= 1ull << bi;
      chosen[r] = bi;
      wsum += ssig[bi];
    }
    for (int r = 0; r < TOPKN; ++r) {
      ids[t * TOPKN + r] = chosen[r];
      wts[t * TOPKN + r] = ssig[chosen[r]] / wsum;
      atomicAdd(&counts[chosen[r]], 1);
    }
  }
}

// ---------------- K1b: offsets + worklist + slot init ----------------
__global__ void k1b_scan(const int* __restrict__ counts, int* __restrict__ eoff,
                         int* __restrict__ tile_e, int* __restrict__ tile_base,
                         int* __restrict__ nt_p,
                         int* __restrict__ slot_tok, float* __restrict__ slot_wt) {
  __shared__ int soff[NEXP + 1];
  __shared__ int s_total;
  int tid = threadIdx.x;
  if (tid == 0) {
    int o = 0, idx = 0;
    for (int e = 0; e < NEXP; ++e) {
      soff[e] = o;
      int ntile = (counts[e] + 127) >> 7;
      for (int t2 = 0; t2 < ntile; ++t2) { tile_e[idx] = e; tile_base[idx] = o + t2 * 128; ++idx; }
      o += ntile << 7;
    }
    soff[NEXP] = o; nt_p[0] = idx; s_total = o;
  }
  __syncthreads();
  if (tid <= NEXP) eoff[tid] = soff[tid];
  int total = s_total;
  for (int i = tid; i < total; i += blockDim.x) { slot_tok[i] = 0; slot_wt[i] = 0.f; }
}

// ---------------- K1c: fill compact slots ----------------
__global__ void k1c_fill(const int* __restrict__ ids, const float* __restrict__ wts,
                         const int* __restrict__ eoff, int* __restrict__ cursor,
                         int* __restrict__ slot_tok, float* __restrict__ slot_wt) {
  int i = blockIdx.x * blockDim.x + threadIdx.x;
  if (i >= T_TOK * TOPKN) return;
  int e = ids[i];
  int s = eoff[e] + atomicAdd(&cursor[e], 1);
  slot_tok[s] = i / TOPKN;
  slot_wt[s] = wts[i] * 2.5f;  // routed_scaling_factor folded in
}

// ---------------- tile GEMM: mid = silu(x@Wg)*(x@Wu), 128x128 tile ----------
__device__ __forceinline__ void tile_mid(
    const float* __restrict__ x, const float* __restrict__ wg, const float* __restrict__ wu,
    const int* __restrict__ slot_tok, int rowbase, int ic0, int IC,
    __hip_bfloat16* __restrict__ mid,
    short* As, short* Bg, short* Bu) {
  int tid = threadIdx.x;
  int wave = tid >> 6, lane = tid & 63;
  int wm = wave >> 2, wn = wave & 3;
  int lr = lane & 15, lk = lane >> 4;

  f32x4 accg[4][2], accu[4][2];
  #pragma unroll
  for (int a = 0; a < 4; ++a)
    #pragma unroll
    for (int b = 0; b < 2; ++b) { accg[a][b] = (f32x4)0.f; accu[a][b] = (f32x4)0.f; }

  for (int k0 = 0; k0 < HDIM; k0 += 64) {
    __syncthreads();
    // stage A: 128 rows x 64 k, fp32 -> bf16
    #pragma unroll
    for (int g = tid; g < 1024; g += 512) {
      int r = g >> 3, c8 = (g & 7) << 3;
      int tok = slot_tok ? slot_tok[rowbase + r] : (rowbase + r);
      const float* src = x + (size_t)tok * HDIM + k0 + c8;
      float4 v0 = *(const float4*)src;
      float4 v1 = *(const float4*)(src + 4);
      bf16x8 tv;
      tv[0] = f2bf(v0.x); tv[1] = f2bf(v0.y); tv[2] = f2bf(v0.z); tv[3] = f2bf(v0.w);
      tv[4] = f2bf(v1.x); tv[5] = f2bf(v1.y); tv[6] = f2bf(v1.z); tv[7] = f2bf(v1.w);
      *(bf16x8*)&As[r * 72 + c8] = tv;
    }
    // stage Bg/Bu transposed bf16 [n][k], XOR-swizzled 16B granules
    #pragma unroll
    for (int g = tid; g < 1024; g += 512) {
      int n = g & 127, kg = g >> 7;
      {
        const float* src = wg + (size_t)(k0 + kg * 8) * IC + ic0 + n;
        bf16x8 tv;
        #pragma unroll
        for (int i = 0; i < 8; ++i) tv[i] = f2bf(src[(size_t)i * IC]);
        *(bf16x8*)&Bg[(n * 8 + (kg ^ (n & 7))) * 8] = tv;
      }
      {
        const float* src = wu + (size_t)(k0 + kg * 8) * IC + ic0 + n;
        bf16x8 tv;
        #pragma unroll
        for (int i = 0; i < 8; ++i) tv[i] = f2bf(src[(size_t)i * IC]);
        *(bf16x8*)&Bu[(n * 8 + (kg ^ (n & 7))) * 8] = tv;
      }
    }
    __syncthreads();
    #pragma unroll
    for (int kk = 0; kk < 2; ++kk) {
      bf16x8 af[4];
      #pragma unroll
      for (int mf = 0; mf < 4; ++mf) {
        int row = wm * 64 + mf * 16 + lr;
        af[mf] = *(bf16x8*)&As[row * 72 + kk * 32 + lk * 8];
      }
      #pragma unroll
      for (int nf = 0; nf < 2; ++nf) {
        int col = wn * 32 + nf * 16 + lr;
        int gidx = (col * 8 + ((kk * 4 + lk) ^ (col & 7))) * 8;
        bf16x8 bgf = *(bf16x8*)&Bg[gidx];
        bf16x8 buf_ = *(bf16x8*)&Bu[gidx];
        #pragma unroll
        for (int mf = 0; mf < 4; ++mf) {
          accg[mf][nf] = __builtin_amdgcn_mfma_f32_16x16x32_bf16(af[mf], bgf, accg[mf][nf], 0, 0, 0);
          accu[mf][nf] = __builtin_amdgcn_mfma_f32_16x16x32_bf16(af[mf], buf_, accu[mf][nf], 0, 0, 0);
        }
      }
    }
  }
  #pragma unroll
  for (int mf = 0; mf < 4; ++mf)
    #pragma unroll
    for (int nf = 0; nf < 2; ++nf)
      #pragma unroll
      for (int r = 0; r < 4; ++r) {
        int row = wm * 64 + mf * 16 + lk * 4 + r;
        int col = wn * 32 + nf * 16 + lr;
        float gv = accg[mf][nf][r], uv = accu[mf][nf][r];
        float h = gv / (1.f + expf(-gv)) * uv;
        mid[(size_t)(rowbase + row) * IC + ic0 + col] = __float2bfloat16(h);
      }
}

// ---------------- tile GEMM: out += (mid @ Wd) * weight ----------------
__device__ __forceinline__ void tile_down(
    const __hip_bfloat16* __restrict__ mid, const float* __restrict__ wd,
    const int* __restrict__ slot_tok, const float* __restrict__ slot_wt,
    int rowbase, int n0, int KD,
    float* __restrict__ out, short* As, short* Bs) {
  int tid = threadIdx.x;
  int wave = tid >> 6, lane = tid & 63;
  int wm = wave >> 2, wn = wave & 3;
  int lr = lane & 15, lk = lane >> 4;

  f32x4 acc[4][2];
  #pragma unroll
  for (int a = 0; a < 4; ++a)
    #pragma unroll
    for (int b = 0; b < 2; ++b) acc[a][b] = (f32x4)0.f;

  for (int k0 = 0; k0 < KD; k0 += 64) {
    __syncthreads();
    #pragma unroll
    for (int g = tid; g < 1024; g += 512) {
      int r = g >> 3, c8 = (g & 7) << 3;
      const __hip_bfloat16* src = mid + (size_t)(rowbase + r) * KD + k0 + c8;
      *(bf16x8*)&As[r * 72 + c8] = *(const bf16x8*)src;
    }
    #pragma unroll
    for (int g = tid; g < 1024; g += 512) {
      int n = g & 127, kg = g >> 7;
      const float* src = wd + (size_t)(k0 + kg * 8) * HDIM + n0 + n;
      bf16x8 tv;
      #pragma unroll
      for (int i = 0; i < 8; ++i) tv[i] = f2bf(src[(size_t)i * HDIM]);
      *(bf16x8*)&Bs[(n * 8 + (kg ^ (n & 7))) * 8] = tv;
    }
    __syncthreads();
    #pragma unroll
    for (int kk = 0; kk < 2; ++kk) {
      bf16x8 af[4];
      #pragma unroll
      for (int mf = 0; mf < 4; ++mf) {
        int row = wm * 64 + mf * 16 + lr;
        af[mf] = *(bf16x8*)&As[row * 72 + kk * 32 + lk * 8];
      }
      #pragma unroll
      for (int nf = 0; nf < 2; ++nf) {
        int col = wn * 32 + nf * 16 + lr;
        bf16x8 bf_ = *(bf16x8*)&Bs[(col * 8 + ((kk * 4 + lk) ^ (col & 7))) * 8];
        #pragma unroll
        for (int mf = 0; mf < 4; ++mf)
          acc[mf][nf] = __builtin_amdgcn_mfma_f32_16x16x32_bf16(af[mf], bf_, acc[mf][nf], 0, 0, 0);
      }
    }
  }
  #pragma unroll
  for (int mf = 0; mf < 4; ++mf)
    #pragma unroll
    for (int nf = 0; nf < 2; ++nf)
      #pragma unroll
      for (int r = 0; r < 4; ++r) {
        int row = wm * 64 + mf * 16 + lk * 4 + r;
        int col = wn * 32 + nf * 16 + lr;
        float v = acc[mf][nf][r];
        if (slot_wt) {
          int s = rowbase + row;
          float w = slot_wt[s];
          if (w != 0.f) {
            int tok = slot_tok[s];
            atomicAdd(&out[(size_t)tok * HDIM + n0 + col], v * w);
          }
        } else {
          atomicAdd(&out[(size_t)(rowbase + row) * HDIM + n0 + col], v);
        }
      }
}

// ---------------- K2 fused: routed + shared mid, worklist grid-stride -------
__global__ __launch_bounds__(512) void k2_fused(
    const float* __restrict__ x, const float* __restrict__ Wg, const float* __restrict__ Wu,
    const float* __restrict__ swg, const float* __restrict__ swu,
    const int* __restrict__ slot_tok, const int* __restrict__ tile_e,
    const int* __restrict__ tile_base, const int* __restrict__ nt_p,
    __hip_bfloat16* __restrict__ mid_r, __hip_bfloat16* __restrict__ mid_s) {
  __shared__ __align__(16) short As[128 * 72];
  __shared__ __align__(16) short Bg[128 * 64];
  __shared__ __align__(16) short Bu[128 * 64];
  int nrt = nt_p[0] * 4;
  int nitems = nrt + 64;
  for (int item = blockIdx.x; item < nitems; item += gridDim.x) {
    if (item < nrt) {
      int tile = item >> 2, c = item & 3;
      int e = tile_e[tile];
      tile_mid(x, Wg + (size_t)e * HDIM * IDIM, Wu + (size_t)e * HDIM * IDIM,
               slot_tok, tile_base[tile], c * 128, IDIM, mid_r, As, Bg, Bu);
    } else {
      int it = item - nrt;
      int mt = it >> 3, c = it & 7;
      tile_mid(x, swg, swu, nullptr, mt * 128, c * 128, SIDIM, mid_s, As, Bg, Bu);
    }
  }
}

// ---------------- K3 fused: routed + shared down, all atomic ----------------
__global__ __launch_bounds__(512) void k3_fused(
    const __hip_bfloat16* __restrict__ mid_r, const __hip_bfloat16* __restrict__ mid_s,
    const float* __restrict__ Wd, const float* __restrict__ swd,
    const int* __restrict__ slot_tok, const float* __restrict__ slot_wt,
    const int* __restrict__ tile_e, const int* __restrict__ tile_base,
    const int* __restrict__ nt_p, float* __restrict__ out) {
  __shared__ __align__(16) short As[128 * 72];
  __shared__ __align__(16) short Bs[128 * 64];
  int nrt = nt_p[0] * 8;
  int nitems = nrt + 64;
  for (int item = blockIdx.x; item < nitems; item += gridDim.x) {
    if (item < nrt) {
      int tile = item >> 3, c = item & 7;
      int e = tile_e[tile];
      tile_down(mid_r, Wd + (size_t)e * IDIM * HDIM, slot_tok, slot_wt,
                tile_base[tile], c * 128, IDIM, out, As, Bs);
    } else {
      int it = item - nrt;
      int mt = it >> 3, c = it & 7;
      tile_down(mid_s, swd, nullptr, nullptr, mt * 128, c * 128, SIDIM, out, As, Bs);
    }
  }
}

// ---------------- launch ----------------
extern "C" void kernel_launch(void* const* d_in, const int* in_sizes, int n_in,
                              void* d_out, int out_size, void* d_ws, size_t ws_size,
                              hipStream_t stream) {
  (void)in_sizes; (void)n_in; (void)out_size; (void)ws_size;
  const float* x      = (const float*)d_in[0];
  const float* gate_w = (const float*)d_in[1];
  const float* ebias  = (const float*)d_in[2];
  const float* wgate  = (const float*)d_in[3];
  const float* wup    = (const float*)d_in[4];
  const float* wdown  = (const float*)d_in[5];
  const float* swg    = (const float*)d_in[6];
  const float* swu    = (const float*)d_in[7];
  const float* swd    = (const float*)d_in[8];
  float* out = (float*)d_out;

  char* ws = (char*)d_ws;
  int*   counts    = (int*)(ws + 0);
  int*   cursor    = (int*)(ws + 256);
  int*   eoff      = (int*)(ws + 512);
  int*   nt_p      = (int*)(ws + 1024);
  int*   tile_e    = (int*)(ws + 1088);
  int*   tile_base = (int*)(ws + 1600);
  int*   ids       = (int*)(ws + 4096);
  float* wts       = (float*)(ws + 28672);
  int*   slot_tok  = (int*)(ws + 53248);
  float* slot_wt   = (float*)(ws + 110592);
  __hip_bfloat16* mid_r = (__hip_bfloat16*)(ws + 167936);
  __hip_bfloat16* mid_s = mid_r + (size_t)CAPS * IDIM;

  k0_init<<<256, 256, 0, stream>>>(counts, cursor, (float4*)out);
  k1_gate<<<T_TOK / 4, 256, 0, stream>>>(x, gate_w, ebias, ids, wts, counts);
  k1b_scan<<<1, 256, 0, stream>>>(counts, eoff, tile_e, tile_base, nt_p, slot_tok, slot_wt);
  k1c_fill<<<(T_TOK * TOPKN + 255) / 256, 256, 0, stream>>>(ids, wts, eoff, cursor, slot_tok, slot_wt);
  k2_fused<<<512, 512, 0, stream>>>(x, wgate, wup, swg, swu, slot_tok, tile_e, tile_base, nt_p, mid_r, mid_s);
  k3_fused<<<768, 512, 0, stream>>>(mid_r, mid_s, wdown, swd, slot_tok, slot_wt, tile_e, tile_base, nt_p, out);
}

// Round 3
// 263.289 us; speedup vs baseline: 2.6320x; 1.3396x over previous
//
#include <hip/hip_runtime.h>
#include <hip/hip_bf16.h>

#define T_TOK 1024
#define HDIM  1024
#define NEXP  64
#define IDIM  512
#define SIDIM 1024
#define NGRP  8
#define GSZ   8
#define TKGN  3
#define TOPKN 6
#define CAPS  14336

typedef __attribute__((ext_vector_type(8))) short bf16x8;
typedef __attribute__((ext_vector_type(4))) float f32x4;

__device__ __forceinline__ short f2bf(float f) {
  union { __hip_bfloat16 h; short s; } u;
  u.h = __float2bfloat16(f);
  return u.s;
}

// ---------------- K0: zero counters + zero out ----------------
__global__ void k0_init(int* counts, int* cursor, float4* out4) {
  int gid = blockIdx.x * blockDim.x + threadIdx.x;
  if (gid < NEXP) { counts[gid] = 0; cursor[gid] = 0; }
  int total4 = T_TOK * HDIM / 4;
  int stride = gridDim.x * blockDim.x;
  for (int i = gid; i < total4; i += stride)
    out4[i] = make_float4(0.f, 0.f, 0.f, 0.f);
}

// ---------------- K1: gating + grouped top-k (4 tokens / block) -------------
__global__ __launch_bounds__(256) void k1_gate(
    const float* __restrict__ x, const float* __restrict__ gw,
    const float* __restrict__ ebias,
    int* __restrict__ ids, float* __restrict__ wts, int* __restrict__ counts) {
  int sub = threadIdx.x >> 6;
  int lane = threadIdx.x & 63;
  int t = blockIdx.x * 4 + sub;
  const float* xr = x + (size_t)t * HDIM;
  double a0 = 0.0, a1 = 0.0, a2 = 0.0, a3 = 0.0;
  for (int h = 0; h < HDIM; h += 4) {
    float4 xv = *(const float4*)(xr + h);
    a0 += (double)xv.x * (double)gw[(h + 0) * NEXP + lane];
    a1 += (double)xv.y * (double)gw[(h + 1) * NEXP + lane];
    a2 += (double)xv.z * (double)gw[(h + 2) * NEXP + lane];
    a3 += (double)xv.w * (double)gw[(h + 3) * NEXP + lane];
  }
  float logit = (float)((a0 + a1) + (a2 + a3));
  float sig = 1.f / (1.f + expf(-logit));
  float sc = sig + ebias[lane];
  __shared__ float s_sc[4][NEXP], s_sig[4][NEXP];
  s_sc[sub][lane] = sc; s_sig[sub][lane] = sig;
  __syncthreads();
  if (lane == 0) {
    const float* ssc = s_sc[sub];
    const float* ssig = s_sig[sub];
    float gsum[NGRP];
    for (int g = 0; g < NGRP; ++g) {
      float m1 = -1e30f; int i1 = -1;
      for (int i = 0; i < GSZ; ++i) {
        float v = ssc[g * GSZ + i];
        if (v > m1) { m1 = v; i1 = i; }
      }
      float m2 = -1e30f;
      for (int i = 0; i < GSZ; ++i) {
        if (i == i1) continue;
        float v = ssc[g * GSZ + i];
        if (v > m2) m2 = v;
      }
      gsum[g] = m1 + m2;
    }
    unsigned gselmask = 0;
    for (int r = 0; r < TKGN; ++r) {
      float best = -1e30f; int bi = 0;
      for (int g = 0; g < NGRP; ++g) {
        if ((gselmask >> g) & 1) continue;
        if (gsum[g] > best) { best = gsum[g]; bi = g; }
      }
      gselmask |= 1u << bi;
    }
    unsigned long long taken = 0;
    int chosen[TOPKN]; float wsum = 0.f;
    for (int r = 0; r < TOPKN; ++r) {
      float best = -1e30f; int bi = 0;
      for (int e = 0; e < NEXP; ++e) {
        if (!((gselmask >> (e >> 3)) & 1)) continue;
        if ((taken >> e) & 1) continue;
        float v = ssc[e];
        if (v > best) { best = v; bi = e; }
      }
      taken |= 1ull << bi;
      chosen[r] = bi;
      wsum += ssig[bi];
    }
    for (int r = 0; r < TOPKN; ++r) {
      ids[t * TOPKN + r] = chosen[r];
      wts[t * TOPKN + r] = ssig[chosen[r]] / wsum;
      atomicAdd(&counts[chosen[r]], 1);
    }
  }
}

// ---------------- K1b: offsets + worklist + slot init ----------------
__global__ void k1b_scan(const int* __restrict__ counts, int* __restrict__ eoff,
                         int* __restrict__ tile_e, int* __restrict__ tile_base,
                         int* __restrict__ nt_p,
                         int* __restrict__ slot_tok, float* __restrict__ slot_wt) {
  __shared__ int soff[NEXP + 1];
  __shared__ int s_total;
  int tid = threadIdx.x;
  if (tid == 0) {
    int o = 0, idx = 0;
    for (int e = 0; e < NEXP; ++e) {
      soff[e] = o;
      int ntile = (counts[e] + 127) >> 7;
      for (int t2 = 0; t2 < ntile; ++t2) { tile_e[idx] = e; tile_base[idx] = o + t2 * 128; ++idx; }
      o += ntile << 7;
    }
    soff[NEXP] = o; nt_p[0] = idx; s_total = o;
  }
  __syncthreads();
  if (tid <= NEXP) eoff[tid] = soff[tid];
  int total = s_total;
  for (int i = tid; i < total; i += blockDim.x) { slot_tok[i] = 0; slot_wt[i] = 0.f; }
}

// ---------------- K1c: fill compact slots ----------------
__global__ void k1c_fill(const int* __restrict__ ids, const float* __restrict__ wts,
                         const int* __restrict__ eoff, int* __restrict__ cursor,
                         int* __restrict__ slot_tok, float* __restrict__ slot_wt) {
  int i = blockIdx.x * blockDim.x + threadIdx.x;
  if (i >= T_TOK * TOPKN) return;
  int e = ids[i];
  int s = eoff[e] + atomicAdd(&cursor[e], 1);
  slot_tok[s] = i / TOPKN;
  slot_wt[s] = wts[i] * 2.5f;  // routed_scaling_factor folded in
}

// ------- tile GEMM: mid = silu(x@Wg)*(x@Wu), 128m x 64n tile, T14 pipeline --
__device__ __forceinline__ void tile_mid(
    const float* __restrict__ x, const float* __restrict__ wg, const float* __restrict__ wu,
    const int* __restrict__ slot_tok, int rowbase, int ic0, int IC,
    __hip_bfloat16* __restrict__ mid,
    short* As, short* Bg, short* Bu) {
  int tid = threadIdx.x;
  int wave = tid >> 6, lane = tid & 63;
  int wm = wave >> 1, wn = wave & 1;
  int lr = lane & 15, lk = lane >> 4;

  // A staging: 2 rows of 8 cols per thread
  int ar = tid >> 3, ac8 = (tid & 7) << 3;
  const float* aptr[2];
  #pragma unroll
  for (int it = 0; it < 2; ++it) {
    int r = ar + it * 64;
    int tok = slot_tok ? slot_tok[rowbase + r] : (rowbase + r);
    aptr[it] = x + (size_t)tok * HDIM + ac8;
  }
  // B staging: one 8-deep k-column per thread
  int bn = tid & 63, bkg = tid >> 6;
  const float* bgp = wg + (size_t)(bkg * 8) * IC + ic0 + bn;
  const float* bup = wu + (size_t)(bkg * 8) * IC + ic0 + bn;
  int bgran = (bn * 8 + (bkg ^ (bn & 7))) * 8;

  f32x4 accg[2][2], accu[2][2];
  #pragma unroll
  for (int a = 0; a < 2; ++a)
    #pragma unroll
    for (int b = 0; b < 2; ++b) { accg[a][b] = (f32x4)0.f; accu[a][b] = (f32x4)0.f; }

  float bgr[8], bur[8];
  #pragma unroll
  for (int i = 0; i < 8; ++i) {
    bgr[i] = bgp[(size_t)i * IC];
    bur[i] = bup[(size_t)i * IC];
  }

  const int NST = HDIM / 64;
  for (int s = 0; s < NST; ++s) {
    int k0 = s * 64;
    // issue A loads before the barrier (latency hides under barrier wait)
    float4 av[2][2];
    #pragma unroll
    for (int it = 0; it < 2; ++it) {
      av[it][0] = *(const float4*)(aptr[it] + k0);
      av[it][1] = *(const float4*)(aptr[it] + k0 + 4);
    }
    __syncthreads();  // previous compute done, LDS free
    #pragma unroll
    for (int it = 0; it < 2; ++it) {
      bf16x8 tv;
      tv[0] = f2bf(av[it][0].x); tv[1] = f2bf(av[it][0].y);
      tv[2] = f2bf(av[it][0].z); tv[3] = f2bf(av[it][0].w);
      tv[4] = f2bf(av[it][1].x); tv[5] = f2bf(av[it][1].y);
      tv[6] = f2bf(av[it][1].z); tv[7] = f2bf(av[it][1].w);
      *(bf16x8*)&As[(ar + it * 64) * 72 + ac8] = tv;
    }
    {
      bf16x8 tg, tu;
      #pragma unroll
      for (int i = 0; i < 8; ++i) { tg[i] = f2bf(bgr[i]); tu[i] = f2bf(bur[i]); }
      *(bf16x8*)&Bg[bgran] = tg;
      *(bf16x8*)&Bu[bgran] = tu;
    }
    __syncthreads();  // tile ready
    // prefetch next B stream (in flight across MFMA + next barrier)
    if (s + 1 < NST) {
      #pragma unroll
      for (int i = 0; i < 8; ++i) {
        bgr[i] = bgp[(size_t)(k0 + 64 + i) * IC];
        bur[i] = bup[(size_t)(k0 + 64 + i) * IC];
      }
    }
    #pragma unroll
    for (int kk = 0; kk < 2; ++kk) {
      bf16x8 af[2];
      #pragma unroll
      for (int mf = 0; mf < 2; ++mf) {
        int row = wm * 32 + mf * 16 + lr;
        af[mf] = *(bf16x8*)&As[row * 72 + kk * 32 + lk * 8];
      }
      #pragma unroll
      for (int nf = 0; nf < 2; ++nf) {
        int col = wn * 32 + nf * 16 + lr;
        int gidx = (col * 8 + ((kk * 4 + lk) ^ (col & 7))) * 8;
        bf16x8 bgf = *(bf16x8*)&Bg[gidx];
        bf16x8 buf_ = *(bf16x8*)&Bu[gidx];
        #pragma unroll
        for (int mf = 0; mf < 2; ++mf) {
          accg[mf][nf] = __builtin_amdgcn_mfma_f32_16x16x32_bf16(af[mf], bgf, accg[mf][nf], 0, 0, 0);
          accu[mf][nf] = __builtin_amdgcn_mfma_f32_16x16x32_bf16(af[mf], buf_, accu[mf][nf], 0, 0, 0);
        }
      }
    }
  }
  #pragma unroll
  for (int mf = 0; mf < 2; ++mf)
    #pragma unroll
    for (int nf = 0; nf < 2; ++nf)
      #pragma unroll
      for (int r = 0; r < 4; ++r) {
        int row = wm * 32 + mf * 16 + lk * 4 + r;
        int col = wn * 32 + nf * 16 + lr;
        float gv = accg[mf][nf][r], uv = accu[mf][nf][r];
        float h = gv / (1.f + expf(-gv)) * uv;
        mid[(size_t)(rowbase + row) * IC + ic0 + col] = __float2bfloat16(h);
      }
}

// ------- tile GEMM: out += (mid @ Wd) * weight, 128m x 64n tile, T14 --------
__device__ __forceinline__ void tile_down(
    const __hip_bfloat16* __restrict__ mid, const float* __restrict__ wd,
    const int* __restrict__ slot_tok, const float* __restrict__ slot_wt,
    int rowbase, int n0, int KD,
    float* __restrict__ out, short* As, short* Bs) {
  int tid = threadIdx.x;
  int wave = tid >> 6, lane = tid & 63;
  int wm = wave >> 1, wn = wave & 1;
  int lr = lane & 15, lk = lane >> 4;

  int ar = tid >> 3, ac8 = (tid & 7) << 3;
  const __hip_bfloat16* aptr[2];
  #pragma unroll
  for (int it = 0; it < 2; ++it)
    aptr[it] = mid + (size_t)(rowbase + ar + it * 64) * KD + ac8;

  int bn = tid & 63, bkg = tid >> 6;
  const float* bp = wd + (size_t)(bkg * 8) * HDIM + n0 + bn;
  int bgran = (bn * 8 + (bkg ^ (bn & 7))) * 8;

  f32x4 acc[2][2];
  #pragma unroll
  for (int a = 0; a < 2; ++a)
    #pragma unroll
    for (int b = 0; b < 2; ++b) acc[a][b] = (f32x4)0.f;

  float br[8];
  #pragma unroll
  for (int i = 0; i < 8; ++i) br[i] = bp[(size_t)i * HDIM];

  const int NST_ = KD / 64;
  for (int s = 0; s < NST_; ++s) {
    int k0 = s * 64;
    bf16x8 avv[2];
    #pragma unroll
    for (int it = 0; it < 2; ++it)
      avv[it] = *(const bf16x8*)(aptr[it] + k0);
    __syncthreads();
    #pragma unroll
    for (int it = 0; it < 2; ++it)
      *(bf16x8*)&As[(ar + it * 64) * 72 + ac8] = avv[it];
    {
      bf16x8 tb;
      #pragma unroll
      for (int i = 0; i < 8; ++i) tb[i] = f2bf(br[i]);
      *(bf16x8*)&Bs[bgran] = tb;
    }
    __syncthreads();
    if (s + 1 < NST_) {
      #pragma unroll
      for (int i = 0; i < 8; ++i)
        br[i] = bp[(size_t)(k0 + 64 + i) * HDIM];
    }
    #pragma unroll
    for (int kk = 0; kk < 2; ++kk) {
      bf16x8 af[2];
      #pragma unroll
      for (int mf = 0; mf < 2; ++mf) {
        int row = wm * 32 + mf * 16 + lr;
        af[mf] = *(bf16x8*)&As[row * 72 + kk * 32 + lk * 8];
      }
      #pragma unroll
      for (int nf = 0; nf < 2; ++nf) {
        int col = wn * 32 + nf * 16 + lr;
        bf16x8 bf_ = *(bf16x8*)&Bs[(col * 8 + ((kk * 4 + lk) ^ (col & 7))) * 8];
        #pragma unroll
        for (int mf = 0; mf < 2; ++mf)
          acc[mf][nf] = __builtin_amdgcn_mfma_f32_16x16x32_bf16(af[mf], bf_, acc[mf][nf], 0, 0, 0);
      }
    }
  }
  #pragma unroll
  for (int mf = 0; mf < 2; ++mf)
    #pragma unroll
    for (int nf = 0; nf < 2; ++nf)
      #pragma unroll
      for (int r = 0; r < 4; ++r) {
        int row = wm * 32 + mf * 16 + lk * 4 + r;
        int col = wn * 32 + nf * 16 + lr;
        float v = acc[mf][nf][r];
        if (slot_wt) {
          int s = rowbase + row;
          float w = slot_wt[s];
          if (w != 0.f) {
            int tok = slot_tok[s];
            atomicAdd(&out[(size_t)tok * HDIM + n0 + col], v * w);
          }
        } else {
          atomicAdd(&out[(size_t)(rowbase + row) * HDIM + n0 + col], v);
        }
      }
}

// ---------------- K2 fused: routed + shared mid ----------------
__global__ __launch_bounds__(512) void k2_fused(
    const float* __restrict__ x, const float* __restrict__ Wg, const float* __restrict__ Wu,
    const float* __restrict__ swg, const float* __restrict__ swu,
    const int* __restrict__ slot_tok, const int* __restrict__ tile_e,
    const int* __restrict__ tile_base, const int* __restrict__ nt_p,
    __hip_bfloat16* __restrict__ mid_r, __hip_bfloat16* __restrict__ mid_s) {
  __shared__ __align__(16) short As[128 * 72];
  __shared__ __align__(16) short Bg[64 * 64];
  __shared__ __align__(16) short Bu[64 * 64];
  int nrt = nt_p[0] * 8;        // IDIM/64 chunks
  int nitems = nrt + 128;       // shared: 8 mt x 16 c
  for (int item = blockIdx.x; item < nitems; item += gridDim.x) {
    if (item < nrt) {
      int tile = item >> 3, c = item & 7;
      int e = tile_e[tile];
      tile_mid(x, Wg + (size_t)e * HDIM * IDIM, Wu + (size_t)e * HDIM * IDIM,
               slot_tok, tile_base[tile], c * 64, IDIM, mid_r, As, Bg, Bu);
    } else {
      int it = item - nrt;
      int mt = it >> 4, c = it & 15;
      tile_mid(x, swg, swu, nullptr, mt * 128, c * 64, SIDIM, mid_s, As, Bg, Bu);
    }
  }
}

// ---------------- K3 fused: routed + shared down, all atomic ----------------
__global__ __launch_bounds__(512) void k3_fused(
    const __hip_bfloat16* __restrict__ mid_r, const __hip_bfloat16* __restrict__ mid_s,
    const float* __restrict__ Wd, const float* __restrict__ swd,
    const int* __restrict__ slot_tok, const float* __restrict__ slot_wt,
    const int* __restrict__ tile_e, const int* __restrict__ tile_base,
    const int* __restrict__ nt_p, float* __restrict__ out) {
  __shared__ __align__(16) short As[128 * 72];
  __shared__ __align__(16) short Bs[64 * 64];
  int nrt = nt_p[0] * 16;       // HDIM/64 chunks
  int nsh = 128;                // shared: 8 mt x 16 c (16 K-steps, run first)
  int nitems = nrt + nsh;
  for (int item = blockIdx.x; item < nitems; item += gridDim.x) {
    if (item < nsh) {
      int mt = item >> 4, c = item & 15;
      tile_down(mid_s, swd, nullptr, nullptr, mt * 128, c * 64, SIDIM, out, As, Bs);
    } else {
      int it = item - nsh;
      int tile = it >> 4, c = it & 15;
      int e = tile_e[tile];
      tile_down(mid_r, Wd + (size_t)e * IDIM * HDIM, slot_tok, slot_wt,
                tile_base[tile], c * 64, IDIM, out, As, Bs);
    }
  }
}

// ---------------- launch ----------------
extern "C" void kernel_launch(void* const* d_in, const int* in_sizes, int n_in,
                              void* d_out, int out_size, void* d_ws, size_t ws_size,
                              hipStream_t stream) {
  (void)in_sizes; (void)n_in; (void)out_size; (void)ws_size;
  const float* x      = (const float*)d_in[0];
  const float* gate_w = (const float*)d_in[1];
  const float* ebias  = (const float*)d_in[2];
  const float* wgate  = (const float*)d_in[3];
  const float* wup    = (const float*)d_in[4];
  const float* wdown  = (const float*)d_in[5];
  const float* swg    = (const float*)d_in[6];
  const float* swu    = (const float*)d_in[7];
  const float* swd    = (const float*)d_in[8];
  float* out = (float*)d_out;

  char* ws = (char*)d_ws;
  int*   counts    = (int*)(ws + 0);
  int*   cursor    = (int*)(ws + 256);
  int*   eoff      = (int*)(ws + 512);
  int*   nt_p      = (int*)(ws + 1024);
  int*   tile_e    = (int*)(ws + 1088);
  int*   tile_base = (int*)(ws + 1600);
  int*   ids       = (int*)(ws + 4096);
  float* wts       = (float*)(ws + 28672);
  int*   slot_tok  = (int*)(ws + 53248);
  float* slot_wt   = (float*)(ws + 110592);
  __hip_bfloat16* mid_r = (__hip_bfloat16*)(ws + 167936);
  __hip_bfloat16* mid_s = mid_r + (size_t)CAPS * IDIM;

  k0_init<<<256, 256, 0, stream>>>(counts, cursor, (float4*)out);
  k1_gate<<<T_TOK / 4, 256, 0, stream>>>(x, gate_w, ebias, ids, wts, counts);
  k1b_scan<<<1, 256, 0, stream>>>(counts, eoff, tile_e, tile_base, nt_p, slot_tok, slot_wt);
  k1c_fill<<<(T_TOK * TOPKN + 255) / 256, 256, 0, stream>>>(ids, wts, eoff, cursor, slot_tok, slot_wt);
  k2_fused<<<640, 512, 0, stream>>>(x, wgate, wup, swg, swu, slot_tok, tile_e, tile_base, nt_p, mid_r, mid_s);
  k3_fused<<<1152, 512, 0, stream>>>(mid_r, mid_s, wdown, swd, slot_tok, slot_wt, tile_e, tile_base, nt_p, out);
}

// Round 4
// 232.503 us; speedup vs baseline: 2.9805x; 1.1324x over previous
//
#include <hip/hip_runtime.h>
#include <hip/hip_bf16.h>

#define T_TOK 1024
#define HDIM  1024
#define NEXP  64
#define IDIM  512
#define SIDIM 1024
#define NGRP  8
#define GSZ   8
#define TKGN  3
#define TOPKN 6
#define CAPS  14336

typedef __attribute__((ext_vector_type(8))) short bf16x8;
typedef __attribute__((ext_vector_type(4))) float f32x4;

__device__ __forceinline__ short f2bf(float f) {
  union { __hip_bfloat16 h; short s; } u;
  u.h = __float2bfloat16(f);
  return u.s;
}
__device__ __forceinline__ float bf2f(short s) {
  union { float f; unsigned u; } c;
  c.u = ((unsigned)(unsigned short)s) << 16;
  return c.f;
}

// one barrier, no vmcnt drain: LDS writes flushed, global loads stay in flight
#define BARRIER() asm volatile("s_waitcnt lgkmcnt(0)\n\ts_barrier" ::: "memory")

// ---------------- K0: zero counters ----------------
__global__ void k0_init(int* counts, int* cursor) {
  int i = threadIdx.x;
  if (i < NEXP) { counts[i] = 0; cursor[i] = 0; }
}

// ---------------- K1: gating + grouped top-k (4 tokens / block) -------------
__global__ __launch_bounds__(256) void k1_gate(
    const float* __restrict__ x, const float* __restrict__ gw,
    const float* __restrict__ ebias,
    int* __restrict__ ids, float* __restrict__ wts, int* __restrict__ counts) {
  int sub = threadIdx.x >> 6;
  int lane = threadIdx.x & 63;
  int t = blockIdx.x * 4 + sub;
  const float* xr = x + (size_t)t * HDIM;
  double a0 = 0.0, a1 = 0.0, a2 = 0.0, a3 = 0.0;
  for (int h = 0; h < HDIM; h += 4) {
    float4 xv = *(const float4*)(xr + h);
    a0 += (double)xv.x * (double)gw[(h + 0) * NEXP + lane];
    a1 += (double)xv.y * (double)gw[(h + 1) * NEXP + lane];
    a2 += (double)xv.z * (double)gw[(h + 2) * NEXP + lane];
    a3 += (double)xv.w * (double)gw[(h + 3) * NEXP + lane];
  }
  float logit = (float)((a0 + a1) + (a2 + a3));
  float sig = 1.f / (1.f + expf(-logit));
  float sc = sig + ebias[lane];
  __shared__ float s_sc[4][NEXP], s_sig[4][NEXP];
  s_sc[sub][lane] = sc; s_sig[sub][lane] = sig;
  __syncthreads();
  if (lane == 0) {
    const float* ssc = s_sc[sub];
    const float* ssig = s_sig[sub];
    float gsum[NGRP];
    for (int g = 0; g < NGRP; ++g) {
      float m1 = -1e30f; int i1 = -1;
      for (int i = 0; i < GSZ; ++i) {
        float v = ssc[g * GSZ + i];
        if (v > m1) { m1 = v; i1 = i; }
      }
      float m2 = -1e30f;
      for (int i = 0; i < GSZ; ++i) {
        if (i == i1) continue;
        float v = ssc[g * GSZ + i];
        if (v > m2) m2 = v;
      }
      gsum[g] = m1 + m2;
    }
    unsigned gselmask = 0;
    for (int r = 0; r < TKGN; ++r) {
      float best = -1e30f; int bi = 0;
      for (int g = 0; g < NGRP; ++g) {
        if ((gselmask >> g) & 1) continue;
        if (gsum[g] > best) { best = gsum[g]; bi = g; }
      }
      gselmask |= 1u << bi;
    }
    unsigned long long taken = 0;
    int chosen[TOPKN]; float wsum = 0.f;
    for (int r = 0; r < TOPKN; ++r) {
      float best = -1e30f; int bi = 0;
      for (int e = 0; e < NEXP; ++e) {
        if (!((gselmask >> (e >> 3)) & 1)) continue;
        if ((taken >> e) & 1) continue;
        float v = ssc[e];
        if (v > best) { best = v; bi = e; }
      }
      taken |= 1ull << bi;
      chosen[r] = bi;
      wsum += ssig[bi];
    }
    for (int r = 0; r < TOPKN; ++r) {
      ids[t * TOPKN + r] = chosen[r];
      wts[t * TOPKN + r] = ssig[chosen[r]] / wsum;
      atomicAdd(&counts[chosen[r]], 1);
    }
  }
}

// ---------------- K1b: offsets + worklist + slot init ----------------
__global__ void k1b_scan(const int* __restrict__ counts, int* __restrict__ eoff,
                         int* __restrict__ tile_e, int* __restrict__ tile_base,
                         int* __restrict__ nt_p, int* __restrict__ slot_tok) {
  __shared__ int soff[NEXP + 1];
  __shared__ int s_total;
  int tid = threadIdx.x;
  if (tid == 0) {
    int o = 0, idx = 0;
    for (int e = 0; e < NEXP; ++e) {
      soff[e] = o;
      int ntile = (counts[e] + 127) >> 7;
      for (int t2 = 0; t2 < ntile; ++t2) { tile_e[idx] = e; tile_base[idx] = o + t2 * 128; ++idx; }
      o += ntile << 7;
    }
    soff[NEXP] = o; nt_p[0] = idx; s_total = o;
  }
  __syncthreads();
  if (tid <= NEXP) eoff[tid] = soff[tid];
  int total = s_total;
  for (int i = tid; i < total; i += blockDim.x) slot_tok[i] = 0;
}

// ---------------- K1c: fill compact slots + token->slot map ----------------
__global__ void k1c_fill(const int* __restrict__ ids,
                         const int* __restrict__ eoff, int* __restrict__ cursor,
                         int* __restrict__ slot_tok, int* __restrict__ tslot) {
  int i = blockIdx.x * blockDim.x + threadIdx.x;
  if (i >= T_TOK * TOPKN) return;
  int e = ids[i];
  int s = eoff[e] + atomicAdd(&cursor[e], 1);
  slot_tok[s] = i / TOPKN;
  tslot[i] = s;
}

// ------- tile GEMM: mid = silu(x@Wg)*(x@Wu), 128m x 64n, dbuf 1-barrier -----
__device__ __forceinline__ void tile_mid(
    const float* __restrict__ x, const float* __restrict__ wg, const float* __restrict__ wu,
    const int* __restrict__ slot_tok, int rowbase, int ic0, int IC,
    __hip_bfloat16* __restrict__ mid, short* As, short* Bg, short* Bu) {
  int tid = threadIdx.x;
  int wave = tid >> 6, lane = tid & 63;
  int wm = wave >> 1, wn = wave & 1;
  int lr = lane & 15, lk = lane >> 4;

  int ar = tid >> 3, kg = tid & 7;
  int aw0 = (ar * 8 + (kg ^ (ar & 7))) * 8;
  int aw1 = ((ar + 64) * 8 + (kg ^ (ar & 7))) * 8;
  int tok0 = slot_tok ? slot_tok[rowbase + ar] : (rowbase + ar);
  int tok1 = slot_tok ? slot_tok[rowbase + ar + 64] : (rowbase + ar + 64);
  const float* aptr0 = x + (size_t)tok0 * HDIM + kg * 8;
  const float* aptr1 = x + (size_t)tok1 * HDIM + kg * 8;

  int bn = tid & 63, bkg = tid >> 6;
  const float* bgp = wg + (size_t)(bkg * 8) * IC + ic0 + bn;
  const float* bup = wu + (size_t)(bkg * 8) * IC + ic0 + bn;
  int bw = (bn * 8 + (bkg ^ (bn & 7))) * 8;

  f32x4 accg[2][2], accu[2][2];
  #pragma unroll
  for (int a = 0; a < 2; ++a)
    #pragma unroll
    for (int b = 0; b < 2; ++b) { accg[a][b] = (f32x4)0.f; accu[a][b] = (f32x4)0.f; }

  float4 a00, a01, a10, a11;
  float bgr[8], bur[8];

  auto LOAD = [&](int s) {
    const float* p0 = aptr0 + s * 64;
    const float* p1 = aptr1 + s * 64;
    a00 = *(const float4*)p0; a01 = *(const float4*)(p0 + 4);
    a10 = *(const float4*)p1; a11 = *(const float4*)(p1 + 4);
    #pragma unroll
    for (int i = 0; i < 8; ++i) {
      bgr[i] = bgp[(size_t)(s * 64 + i) * IC];
      bur[i] = bup[(size_t)(s * 64 + i) * IC];
    }
  };
  auto STORE = [&](int b) {
    short* as = As + b * 8192;
    short* bg = Bg + b * 4096;
    short* bu = Bu + b * 4096;
    bf16x8 t0, t1;
    t0[0] = f2bf(a00.x); t0[1] = f2bf(a00.y); t0[2] = f2bf(a00.z); t0[3] = f2bf(a00.w);
    t0[4] = f2bf(a01.x); t0[5] = f2bf(a01.y); t0[6] = f2bf(a01.z); t0[7] = f2bf(a01.w);
    t1[0] = f2bf(a10.x); t1[1] = f2bf(a10.y); t1[2] = f2bf(a10.z); t1[3] = f2bf(a10.w);
    t1[4] = f2bf(a11.x); t1[5] = f2bf(a11.y); t1[6] = f2bf(a11.z); t1[7] = f2bf(a11.w);
    *(bf16x8*)&as[aw0] = t0;
    *(bf16x8*)&as[aw1] = t1;
    bf16x8 tg, tu;
    #pragma unroll
    for (int i = 0; i < 8; ++i) { tg[i] = f2bf(bgr[i]); tu[i] = f2bf(bur[i]); }
    *(bf16x8*)&bg[bw] = tg;
    *(bf16x8*)&bu[bw] = tu;
  };
  auto COMPUTE = [&](int b) {
    const short* as = As + b * 8192;
    const short* bg = Bg + b * 4096;
    const short* bu = Bu + b * 4096;
    #pragma unroll
    for (int kk = 0; kk < 2; ++kk) {
      bf16x8 af[2];
      #pragma unroll
      for (int mf = 0; mf < 2; ++mf) {
        int row = wm * 32 + mf * 16 + lr;
        af[mf] = *(const bf16x8*)&as[(row * 8 + ((kk * 4 + lk) ^ (row & 7))) * 8];
      }
      #pragma unroll
      for (int nf = 0; nf < 2; ++nf) {
        int col = wn * 32 + nf * 16 + lr;
        int gi = (col * 8 + ((kk * 4 + lk) ^ (col & 7))) * 8;
        bf16x8 bgf = *(const bf16x8*)&bg[gi];
        bf16x8 buf_ = *(const bf16x8*)&bu[gi];
        #pragma unroll
        for (int mf = 0; mf < 2; ++mf) {
          accg[mf][nf] = __builtin_amdgcn_mfma_f32_16x16x32_bf16(af[mf], bgf, accg[mf][nf], 0, 0, 0);
          accu[mf][nf] = __builtin_amdgcn_mfma_f32_16x16x32_bf16(af[mf], buf_, accu[mf][nf], 0, 0, 0);
        }
      }
    }
  };

  const int NST = HDIM / 64;  // 16 (even)
  LOAD(0);
  STORE(0);
  LOAD(1);
  BARRIER();
  for (int s = 0; s < NST; ++s) {
    COMPUTE(s & 1);
    if (s + 1 < NST) {
      STORE((s + 1) & 1);
      if (s + 2 < NST) LOAD(s + 2);
      BARRIER();
    }
  }

  #pragma unroll
  for (int mf = 0; mf < 2; ++mf)
    #pragma unroll
    for (int nf = 0; nf < 2; ++nf)
      #pragma unroll
      for (int r = 0; r < 4; ++r) {
        int row = wm * 32 + mf * 16 + lk * 4 + r;
        int col = wn * 32 + nf * 16 + lr;
        float gv = accg[mf][nf][r], uv = accu[mf][nf][r];
        float h = gv / (1.f + expf(-gv)) * uv;
        mid[(size_t)(rowbase + row) * IC + ic0 + col] = __float2bfloat16(h);
      }
}

// ------- tile GEMM: dout = mid @ Wd (plain bf16 store), dbuf 1-barrier ------
__device__ __forceinline__ void tile_down(
    const __hip_bfloat16* __restrict__ mid, const float* __restrict__ wd,
    int rowbase, int n0, int KD,
    __hip_bfloat16* __restrict__ dout, short* As, short* Bs) {
  int tid = threadIdx.x;
  int wave = tid >> 6, lane = tid & 63;
  int wm = wave >> 1, wn = wave & 1;
  int lr = lane & 15, lk = lane >> 4;

  int ar = tid >> 3, kg = tid & 7;
  int aw0 = (ar * 8 + (kg ^ (ar & 7))) * 8;
  int aw1 = ((ar + 64) * 8 + (kg ^ (ar & 7))) * 8;
  const __hip_bfloat16* aptr0 = mid + (size_t)(rowbase + ar) * KD + kg * 8;
  const __hip_bfloat16* aptr1 = mid + (size_t)(rowbase + ar + 64) * KD + kg * 8;

  int bn = tid & 63, bkg = tid >> 6;
  const float* bp = wd + (size_t)(bkg * 8) * HDIM + n0 + bn;
  int bw = (bn * 8 + (bkg ^ (bn & 7))) * 8;

  f32x4 acc[2][2];
  #pragma unroll
  for (int a = 0; a < 2; ++a)
    #pragma unroll
    for (int b = 0; b < 2; ++b) acc[a][b] = (f32x4)0.f;

  bf16x8 av0, av1;
  float br[8];

  auto LOAD = [&](int s) {
    av0 = *(const bf16x8*)(aptr0 + s * 64);
    av1 = *(const bf16x8*)(aptr1 + s * 64);
    #pragma unroll
    for (int i = 0; i < 8; ++i) br[i] = bp[(size_t)(s * 64 + i) * HDIM];
  };
  auto STORE = [&](int b) {
    short* as = As + b * 8192;
    short* bs = Bs + b * 4096;
    *(bf16x8*)&as[aw0] = av0;
    *(bf16x8*)&as[aw1] = av1;
    bf16x8 tb;
    #pragma unroll
    for (int i = 0; i < 8; ++i) tb[i] = f2bf(br[i]);
    *(bf16x8*)&bs[bw] = tb;
  };
  auto COMPUTE = [&](int b) {
    const short* as = As + b * 8192;
    const short* bs = Bs + b * 4096;
    #pragma unroll
    for (int kk = 0; kk < 2; ++kk) {
      bf16x8 af[2];
      #pragma unroll
      for (int mf = 0; mf < 2; ++mf) {
        int row = wm * 32 + mf * 16 + lr;
        af[mf] = *(const bf16x8*)&as[(row * 8 + ((kk * 4 + lk) ^ (row & 7))) * 8];
      }
      #pragma unroll
      for (int nf = 0; nf < 2; ++nf) {
        int col = wn * 32 + nf * 16 + lr;
        bf16x8 bf_ = *(const bf16x8*)&bs[(col * 8 + ((kk * 4 + lk) ^ (col & 7))) * 8];
        #pragma unroll
        for (int mf = 0; mf < 2; ++mf)
          acc[mf][nf] = __builtin_amdgcn_mfma_f32_16x16x32_bf16(af[mf], bf_, acc[mf][nf], 0, 0, 0);
      }
    }
  };

  const int NST = KD / 64;  // 8 or 16 (even)
  LOAD(0);
  STORE(0);
  LOAD(1);
  BARRIER();
  for (int s = 0; s < NST; ++s) {
    COMPUTE(s & 1);
    if (s + 1 < NST) {
      STORE((s + 1) & 1);
      if (s + 2 < NST) LOAD(s + 2);
      BARRIER();
    }
  }

  #pragma unroll
  for (int mf = 0; mf < 2; ++mf)
    #pragma unroll
    for (int nf = 0; nf < 2; ++nf)
      #pragma unroll
      for (int r = 0; r < 4; ++r) {
        int row = wm * 32 + mf * 16 + lk * 4 + r;
        int col = wn * 32 + nf * 16 + lr;
        dout[(size_t)(rowbase + row) * HDIM + n0 + col] = __float2bfloat16(acc[mf][nf][r]);
      }
}

// ---------------- K2 fused: routed + shared mid ----------------
__global__ __launch_bounds__(512) void k2_fused(
    const float* __restrict__ x, const float* __restrict__ Wg, const float* __restrict__ Wu,
    const float* __restrict__ swg, const float* __restrict__ swu,
    const int* __restrict__ slot_tok, const int* __restrict__ tile_e,
    const int* __restrict__ tile_base, const int* __restrict__ nt_p,
    __hip_bfloat16* __restrict__ mid_r, __hip_bfloat16* __restrict__ mid_s) {
  __shared__ __align__(16) short As[2 * 8192];
  __shared__ __align__(16) short Bg[2 * 4096];
  __shared__ __align__(16) short Bu[2 * 4096];
  int nrt = nt_p[0] * 8;        // IDIM/64 chunks
  int nitems = nrt + 128;       // shared: 8 mt x 16 c
  for (int item = blockIdx.x; item < nitems; item += gridDim.x) {
    if (item < nrt) {
      int tile = item >> 3, c = item & 7;
      int e = tile_e[tile];
      tile_mid(x, Wg + (size_t)e * HDIM * IDIM, Wu + (size_t)e * HDIM * IDIM,
               slot_tok, tile_base[tile], c * 64, IDIM, mid_r, As, Bg, Bu);
    } else {
      int it = item - nrt;
      int mt = it >> 4, c = it & 15;
      tile_mid(x, swg, swu, nullptr, mt * 128, c * 64, SIDIM, mid_s, As, Bg, Bu);
    }
  }
}

// ---------------- K3 fused: routed + shared down, plain stores --------------
__global__ __launch_bounds__(512) void k3_fused(
    const __hip_bfloat16* __restrict__ mid_r, const __hip_bfloat16* __restrict__ mid_s,
    const float* __restrict__ Wd, const float* __restrict__ swd,
    const int* __restrict__ tile_e, const int* __restrict__ tile_base,
    const int* __restrict__ nt_p,
    __hip_bfloat16* __restrict__ dout_r, __hip_bfloat16* __restrict__ dout_s) {
  __shared__ __align__(16) short As[2 * 8192];
  __shared__ __align__(16) short Bs[2 * 4096];
  int nrt = nt_p[0] * 16;       // HDIM/64 chunks
  int nsh = 128;                // shared: 8 mt x 16 c (16 K-steps, run first)
  int nitems = nrt + nsh;
  for (int item = blockIdx.x; item < nitems; item += gridDim.x) {
    if (item < nsh) {
      int mt = item >> 4, c = item & 15;
      tile_down(mid_s, swd, mt * 128, c * 64, SIDIM, dout_s, As, Bs);
    } else {
      int it = item - nsh;
      int tile = it >> 4, c = it & 15;
      int e = tile_e[tile];
      tile_down(mid_r, Wd + (size_t)e * IDIM * HDIM, tile_base[tile], c * 64, IDIM,
                dout_r, As, Bs);
    }
  }
}

// ---------------- K4: combine per token ----------------
__global__ __launch_bounds__(128) void k4_combine(
    const __hip_bfloat16* __restrict__ dout_r, const __hip_bfloat16* __restrict__ dout_s,
    const int* __restrict__ tslot, const float* __restrict__ wts,
    float* __restrict__ out) {
  int t = blockIdx.x;
  int tid = threadIdx.x;
  int sl[TOPKN]; float w[TOPKN];
  #pragma unroll
  for (int r = 0; r < TOPKN; ++r) {
    sl[r] = tslot[t * TOPKN + r];
    w[r] = wts[t * TOPKN + r] * 2.5f;
  }
  int h0 = tid * 8;  // 128 threads x 8 = 1024
  float acc[8];
  bf16x8 vs = *(const bf16x8*)((const short*)dout_s + (size_t)t * HDIM + h0);
  #pragma unroll
  for (int j = 0; j < 8; ++j) acc[j] = bf2f(vs[j]);
  #pragma unroll
  for (int r = 0; r < TOPKN; ++r) {
    bf16x8 v = *(const bf16x8*)((const short*)dout_r + (size_t)sl[r] * HDIM + h0);
    #pragma unroll
    for (int j = 0; j < 8; ++j) acc[j] += w[r] * bf2f(v[j]);
  }
  float* op = out + (size_t)t * HDIM + h0;
  float4 o0 = make_float4(acc[0], acc[1], acc[2], acc[3]);
  float4 o1 = make_float4(acc[4], acc[5], acc[6], acc[7]);
  *(float4*)op = o0;
  *(float4*)(op + 4) = o1;
}

// ---------------- launch ----------------
extern "C" void kernel_launch(void* const* d_in, const int* in_sizes, int n_in,
                              void* d_out, int out_size, void* d_ws, size_t ws_size,
                              hipStream_t stream) {
  (void)in_sizes; (void)n_in; (void)out_size; (void)ws_size;
  const float* x      = (const float*)d_in[0];
  const float* gate_w = (const float*)d_in[1];
  const float* ebias  = (const float*)d_in[2];
  const float* wgate  = (const float*)d_in[3];
  const float* wup    = (const float*)d_in[4];
  const float* wdown  = (const float*)d_in[5];
  const float* swg    = (const float*)d_in[6];
  const float* swu    = (const float*)d_in[7];
  const float* swd    = (const float*)d_in[8];
  float* out = (float*)d_out;

  char* ws = (char*)d_ws;
  int*   counts    = (int*)(ws + 0);
  int*   cursor    = (int*)(ws + 256);
  int*   eoff      = (int*)(ws + 512);
  int*   nt_p      = (int*)(ws + 1024);
  int*   tile_e    = (int*)(ws + 1088);
  int*   tile_base = (int*)(ws + 1600);
  int*   ids       = (int*)(ws + 4096);
  float* wts       = (float*)(ws + 28672);
  int*   tslot     = (int*)(ws + 53248);
  int*   slot_tok  = (int*)(ws + 77824);
  __hip_bfloat16* mid_r  = (__hip_bfloat16*)(ws + 135168);
  __hip_bfloat16* mid_s  = mid_r + (size_t)CAPS * IDIM;
  __hip_bfloat16* dout_r = (__hip_bfloat16*)(ws + 16912384);
  __hip_bfloat16* dout_s = dout_r + (size_t)CAPS * HDIM;

  k0_init<<<1, 128, 0, stream>>>(counts, cursor);
  k1_gate<<<T_TOK / 4, 256, 0, stream>>>(x, gate_w, ebias, ids, wts, counts);
  k1b_scan<<<1, 256, 0, stream>>>(counts, eoff, tile_e, tile_base, nt_p, slot_tok);
  k1c_fill<<<(T_TOK * TOPKN + 255) / 256, 256, 0, stream>>>(ids, eoff, cursor, slot_tok, tslot);
  k2_fused<<<640, 512, 0, stream>>>(x, wgate, wup, swg, swu, slot_tok, tile_e, tile_base, nt_p, mid_r, mid_s);
  k3_fused<<<1152, 512, 0, stream>>>(mid_r, mid_s, wdown, swd, tile_e, tile_base, nt_p, dout_r, dout_s);
  k4_combine<<<T_TOK, 128, 0, stream>>>(dout_r, dout_s, tslot, wts, out);
}